// Round 5
// baseline (1117.214 us; speedup 1.0000x reference)
//
#include <hip/hip_runtime.h>

// GCN 2-layer forward for MI355X (gfx950).
// Dtype detected on-device (f32 vs bf16 harness conversion).
// Rows pre-scaled by dinv so aggregation is a plain sum.
// Edges are coarse-partitioned into 128-node buckets (packed (src<<7)|dstlow,
// 4B/edge); aggregation scatters into per-block LDS f32 accumulators via
// ds_add_f32 — no fine CSR, no scattered global writes (the R3/R4 kbucket's
// ~110MB write-amplification is gone).

typedef unsigned short u16;
typedef __attribute__((ext_vector_type(8))) short short8;   // 8 bf16
typedef __attribute__((ext_vector_type(4))) float f32x4;

__device__ __forceinline__ float bf2f(u16 u) {
  return __uint_as_float(((unsigned int)u) << 16);
}
__device__ __forceinline__ u16 f2bf(float f) {
  unsigned int u = __float_as_uint(f);
  u += 0x7fffu + ((u >> 16) & 1u);
  return (u16)(u >> 16);
}

// ---- dtype detection: bf16-reinterp of f32 data shows huge exponents ----
__global__ __launch_bounds__(256) void kdetect(const u16* __restrict__ w,
                                               int n16, int* __restrict__ mode) {
  __shared__ float red[4];
  float mx = 0.f;
  for (int i = threadIdx.x; i < n16; i += 256) {
    float av = fabsf(bf2f(w[i]));
    if (!(av <= 1e6f)) av = 3e38f;
    mx = fmaxf(mx, av);
  }
  #pragma unroll
  for (int off = 32; off >= 1; off >>= 1) mx = fmaxf(mx, __shfl_xor(mx, off, 64));
  if ((threadIdx.x & 63) == 0) red[threadIdx.x >> 6] = mx;
  __syncthreads();
  if (threadIdx.x == 0) {
    float m2 = fmaxf(fmaxf(red[0], red[1]), fmaxf(red[2], red[3]));
    mode[0] = (m2 > 1e6f) ? 1 : 0;       // 1 = float32 inputs, 0 = bf16
  }
}

__global__ void kconvw(const void* __restrict__ W1r, const void* __restrict__ b1r,
                       const void* __restrict__ W2r, const void* __restrict__ b2r,
                       const int* __restrict__ mode, u16* __restrict__ W1b,
                       float* __restrict__ b1f, float* __restrict__ W2f,
                       float* __restrict__ b2f) {
  int m = mode[0];
  int gid = blockIdx.x * 256 + threadIdx.x, stride = gridDim.x * 256;
  for (int i = gid; i < 8192; i += stride)
    W1b[i] = m ? f2bf(((const float*)W1r)[i]) : ((const u16*)W1r)[i];
  for (int i = gid; i < 1024; i += stride)
    W2f[i] = m ? ((const float*)W2r)[i] : bf2f(((const u16*)W2r)[i]);
  for (int i = gid; i < 64; i += stride)
    b1f[i] = m ? ((const float*)b1r)[i] : bf2f(((const u16*)b1r)[i]);
  for (int i = gid; i < 16; i += stride)
    b2f[i] = m ? ((const float*)b2r)[i] : bf2f(((const u16*)b2r)[i]);
}

// degree count, 4 edges/thread
__global__ __launch_bounds__(256) void kdeg(const int* __restrict__ dst,
                                            int* __restrict__ degi, int E) {
  int i0 = (blockIdx.x * 256 + threadIdx.x) * 4;
  if (i0 + 3 < E) {
    int4 d4 = *(const int4*)(dst + i0);
    atomicAdd(&degi[d4.x], 1);
    atomicAdd(&degi[d4.y], 1);
    atomicAdd(&degi[d4.z], 1);
    atomicAdd(&degi[d4.w], 1);
  } else {
    for (int j = 0; j < 4; ++j)
      if (i0 + j < E) atomicAdd(&degi[dst[i0 + j]], 1);
  }
}

// dinv = (deg+1)^-0.5 ; ccnt[bucket] = sum of deg over the bucket's 128 nodes.
// One block = 256 nodes = 2 buckets (waves 0,1 -> bucket 2b; 2,3 -> 2b+1).
__global__ __launch_bounds__(256) void kdinvc(const int* __restrict__ degi,
                                              float* __restrict__ dinv,
                                              int* __restrict__ ccnt, int N) {
  __shared__ int red[4];
  int tid = threadIdx.x, wv = tid >> 6;
  int i = blockIdx.x * 256 + tid;
  int d = (i < N) ? degi[i] : 0;
  if (i < N) dinv[i] = rsqrtf((float)(d + 1));
  int s = d;
  #pragma unroll
  for (int off = 32; off >= 1; off >>= 1) s += __shfl_xor(s, off, 64);
  if ((tid & 63) == 0) red[wv] = s;
  __syncthreads();
  if (tid == 0) {
    ccnt[2 * blockIdx.x] = red[0] + red[1];
    ccnt[2 * blockIdx.x + 1] = red[2] + red[3];
  }
}

// single-block exclusive scan of ccnt[NB] (NB <= 1024) -> bstart, cursor.
__global__ __launch_bounds__(1024) void kscanb(const int* __restrict__ ccnt, int NB,
                                               int* __restrict__ bstart,
                                               int* __restrict__ cursor) {
  __shared__ int wsum[16], wexcl[16];
  int tid = threadIdx.x, lane = tid & 63, wv = tid >> 6;
  int v = (tid < NB) ? ccnt[tid] : 0;
  int s = v;
  #pragma unroll
  for (int off = 1; off < 64; off <<= 1) {
    int t = __shfl_up(s, off, 64);
    if (lane >= off) s += t;
  }
  if (lane == 63) wsum[wv] = s;
  __syncthreads();
  if (tid < 16) {
    int ws = wsum[tid], sc = ws;
    #pragma unroll
    for (int off = 1; off < 16; off <<= 1) {
      int t = __shfl_up(sc, off, 16);
      if (tid >= off) sc += t;
    }
    wexcl[tid] = sc - ws;
  }
  __syncthreads();
  int incl = wexcl[wv] + s;
  if (tid < NB) { bstart[tid] = incl - v; cursor[tid] = incl - v; }
  if (tid == NB - 1) bstart[NB] = incl;   // = E
}

// Partition edges into buckets: etmp[slot] = (src<<7)|(dst&127), grouped by
// bucket = dst>>7. Per-block LDS histogram -> one global atomicAdd per
// (block,bucket) -> contiguous runs (write-amp ~3x instead of ~16x).
__global__ __launch_bounds__(256) void kpart(const int* __restrict__ src,
                                             const int* __restrict__ dst,
                                             int* __restrict__ cursor,
                                             int* __restrict__ etmp,
                                             int E, int NB) {
  __shared__ int hist[1024], basep[1024];
  int tid = threadIdx.x;
  for (int i = tid; i < 1024; i += 256) hist[i] = 0;
  __syncthreads();
  int e0 = blockIdx.x * 4096 + tid * 16;
  int pk[16], off[16], cb[16];
  if (e0 + 15 < E) {
    int4 s4[4], d4[4];
    #pragma unroll
    for (int u = 0; u < 4; ++u) {
      s4[u] = ((const int4*)(src + e0))[u];
      d4[u] = ((const int4*)(dst + e0))[u];
    }
    const int* sp = (const int*)s4;
    const int* dp = (const int*)d4;
    #pragma unroll
    for (int k = 0; k < 16; ++k) {
      int s = sp[k], d = dp[k];
      cb[k] = d >> 7;
      pk[k] = (s << 7) | (d & 127);
      off[k] = atomicAdd(&hist[cb[k]], 1);
    }
  } else {
    #pragma unroll
    for (int k = 0; k < 16; ++k) {
      int e = e0 + k;
      cb[k] = -1;
      if (e < E) {
        int s = src[e], d = dst[e];
        cb[k] = d >> 7;
        pk[k] = (s << 7) | (d & 127);
        off[k] = atomicAdd(&hist[cb[k]], 1);
      }
    }
  }
  __syncthreads();
  for (int i = tid; i < NB; i += 256)
    if (hist[i]) basep[i] = atomicAdd(&cursor[i], hist[i]);
  __syncthreads();
  if (e0 + 15 < E) {
    #pragma unroll
    for (int k = 0; k < 16; ++k) etmp[basep[cb[k]] + off[k]] = pk[k];
  } else {
    #pragma unroll
    for (int k = 0; k < 16; ++k)
      if (cb[k] >= 0) etmp[basep[cb[k]] + off[k]] = pk[k];
  }
}

// h1s = (x @ W1) * dinv[row], bf16 out. One wave per 16-row tile.
__global__ __launch_bounds__(256) void kgemm1(const void* __restrict__ xraw,
                                              const u16* __restrict__ W1b,
                                              const int* __restrict__ mode,
                                              const float* __restrict__ dinv,
                                              u16* __restrict__ h1s, int n) {
  int mflag = mode[0];
  int wid = blockIdx.x * 4 + (threadIdx.x >> 6);
  int row0 = wid * 16;
  if (row0 >= n) return;
  int lane = threadIdx.x & 63;
  int m = lane & 15, q = lane >> 4;

  short8 bfrag[4][4];
  for (int jb = 0; jb < 4; ++jb)
    for (int kb = 0; kb < 4; ++kb) {
      short8 f;
      #pragma unroll
      for (int j = 0; j < 8; ++j)
        f[j] = (short)W1b[(kb * 32 + q * 8 + j) * 64 + jb * 16 + m];
      bfrag[jb][kb] = f;
    }

  f32x4 acc[4];
  #pragma unroll
  for (int jb = 0; jb < 4; ++jb) acc[jb] = (f32x4){0.f, 0.f, 0.f, 0.f};

  #pragma unroll
  for (int kb = 0; kb < 4; ++kb) {
    short8 a;
    if (mflag) {
      const float* xf = (const float*)xraw + (size_t)(row0 + m) * 128 + kb * 32 + q * 8;
      float4 u0 = ((const float4*)xf)[0];
      float4 u1 = ((const float4*)xf)[1];
      a[0] = (short)f2bf(u0.x); a[1] = (short)f2bf(u0.y);
      a[2] = (short)f2bf(u0.z); a[3] = (short)f2bf(u0.w);
      a[4] = (short)f2bf(u1.x); a[5] = (short)f2bf(u1.y);
      a[6] = (short)f2bf(u1.z); a[7] = (short)f2bf(u1.w);
    } else {
      a = *(const short8*)((const u16*)xraw + (size_t)(row0 + m) * 128 + kb * 32 + q * 8);
    }
    #pragma unroll
    for (int jb = 0; jb < 4; ++jb)
      acc[jb] = __builtin_amdgcn_mfma_f32_16x16x32_bf16(a, bfrag[jb][kb], acc[jb], 0, 0, 0);
  }

  #pragma unroll
  for (int r = 0; r < 4; ++r) {
    float dv = dinv[row0 + q * 4 + r];
    #pragma unroll
    for (int jb = 0; jb < 4; ++jb)
      h1s[(row0 + q * 4 + r) * 64 + jb * 16 + m] = f2bf(acc[jb][r] * dv);
  }
}

// Layer-1: one block per 128-node bucket. LDS f32 accumulators; waves stream
// packed edges, gather h1s rows (2 edges/iter, dword bf16-pairs), ds_add into
// LDS. Epilogue: bias+relu, fused GEMM2 (x W2), scale by dinv -> h2s.
__global__ __launch_bounds__(512) void kagg1f(
    const u16* __restrict__ h1s, const int* __restrict__ etmp,
    const int* __restrict__ bstart, const float* __restrict__ dinv,
    const float* __restrict__ b1f, const float* __restrict__ W2f,
    float* __restrict__ h2s, int N) {
  __shared__ float acc[128 * 64];       // 32 KB
  __shared__ float W2s[64 * 17];
  int tid = threadIdx.x;
  for (int i = tid; i < 1024; i += 512)
    W2s[(i >> 4) * 17 + (i & 15)] = W2f[i];
  for (int i = tid; i < 128 * 64; i += 512) acc[i] = 0.f;
  __syncthreads();

  int bk = blockIdx.x;
  int beg = bstart[bk], end = bstart[bk + 1];
  int lane = tid & 63, wv = tid >> 6;
  const unsigned int* h1s32 = (const unsigned int*)h1s;   // 32 dwords/row
  int half = lane >> 5;          // which of 2 edges this half-wave handles
  int fl = lane & 31;            // dword index in the 64-feature row

  for (int base = beg + wv * 64; base < end; base += 512) {
    int idx = base + lane;
    int pk = etmp[(idx < end) ? idx : (end - 1)];
    int cnt = min(64, end - base);
    int k = 0;
    for (; k + 2 <= cnt; k += 2) {
      int pke = __shfl(pk, k + half, 64);
      int s = pke >> 7, dl = pke & 127;
      unsigned int g = h1s32[s * 32 + fl];
      atomicAdd(&acc[dl * 64 + fl * 2],     bf2f((u16)(g & 0xffff)));
      atomicAdd(&acc[dl * 64 + fl * 2 + 1], bf2f((u16)(g >> 16)));
    }
    for (; k < cnt; ++k) {
      int pke = __shfl(pk, k, 64);
      if (half == 0) {
        int s = pke >> 7, dl = pke & 127;
        unsigned int g = h1s32[s * 32 + fl];
        atomicAdd(&acc[dl * 64 + fl * 2],     bf2f((u16)(g & 0xffff)));
        atomicAdd(&acc[dl * 64 + fl * 2 + 1], bf2f((u16)(g >> 16)));
      }
    }
  }
  __syncthreads();

  // epilogue: 8 waves x 16 nodes
  int cc = lane & 15, g = lane >> 4;
  for (int nd = wv; nd < 128; nd += 8) {
    int node = (bk << 7) + nd;
    if (node >= N) break;                 // uniform within wave
    float dv = dinv[node];
    float self = bf2f(h1s[node * 64 + lane]);
    float v = fmaxf(dv * (acc[nd * 64 + lane] + self) + b1f[lane], 0.f);
    float p = 0.f;
    #pragma unroll
    for (int j0 = 0; j0 < 16; ++j0)
      p = fmaf(__shfl(v, g * 16 + j0, 64), W2s[(g * 16 + j0) * 17 + cc], p);
    p += __shfl_xor(p, 16, 64);
    p += __shfl_xor(p, 32, 64);
    if (g == 0) h2s[node * 16 + cc] = p * dv;
  }
}

// Layer-2: same bucket structure; quarter-wave per edge (4/iter); epilogue
// does bias+relu+log_softmax over the 16 classes and stores output.
__global__ __launch_bounds__(512) void kagg2f(
    const float* __restrict__ h2s, const int* __restrict__ etmp,
    const int* __restrict__ bstart, const float* __restrict__ dinv,
    const float* __restrict__ b2f, const int* __restrict__ mode,
    void* __restrict__ out, int N) {
  __shared__ float acc[128 * 16];        // 8 KB
  int mflag = mode[0];
  int tid = threadIdx.x;
  for (int i = tid; i < 128 * 16; i += 512) acc[i] = 0.f;
  __syncthreads();

  int bk = blockIdx.x;
  int beg = bstart[bk], end = bstart[bk + 1];
  int lane = tid & 63, wv = tid >> 6;
  int c = lane & 15, q = lane >> 4;

  for (int base = beg + wv * 64; base < end; base += 512) {
    int idx = base + lane;
    int pk = etmp[(idx < end) ? idx : (end - 1)];
    int cnt = min(64, end - base);
    int k = 0;
    for (; k + 4 <= cnt; k += 4) {
      int pke = __shfl(pk, k + q, 64);
      int s = pke >> 7, dl = pke & 127;
      atomicAdd(&acc[dl * 16 + c], h2s[s * 16 + c]);
    }
    for (; k < cnt; ++k) {
      int pke = __shfl(pk, k, 64);
      if (q == 0) {
        int s = pke >> 7, dl = pke & 127;
        atomicAdd(&acc[dl * 16 + c], h2s[s * 16 + c]);
      }
    }
  }
  __syncthreads();

  // epilogue: 32 quarter-waves x 4 nodes
  int qq = tid >> 4;
  for (int nd = qq; nd < 128; nd += 32) {
    int node = (bk << 7) + nd;
    if (node < N) {
      float v = dinv[node] * (acc[nd * 16 + c] + h2s[node * 16 + c]) + b2f[c];
      v = fmaxf(v, 0.f);
      float m = v;
      #pragma unroll
      for (int off = 8; off >= 1; off >>= 1) m = fmaxf(m, __shfl_xor(m, off, 16));
      float ex = __expf(v - m);
      float s = ex;
      #pragma unroll
      for (int off = 8; off >= 1; off >>= 1) s += __shfl_xor(s, off, 16);
      float r = v - m - __logf(s);
      size_t oidx = (size_t)node * 16 + c;
      if (mflag) ((float*)out)[oidx] = r;
      else       ((u16*)out)[oidx] = f2bf(r);
    }
  }
}

extern "C" void kernel_launch(void* const* d_in, const int* in_sizes, int n_in,
                              void* d_out, int out_size, void* d_ws, size_t ws_size,
                              hipStream_t stream) {
  const void* x  = d_in[0];
  const int* ei  = (const int*)d_in[1];
  const void* W1 = d_in[2];
  const void* b1 = d_in[3];
  const void* W2 = d_in[4];
  const void* b2 = d_in[5];

  const int N = in_sizes[0] / 128;
  const int E = in_sizes[1] / 2;
  const int* src = ei;
  const int* dst = ei + E;
  const int NB = (N + 127) >> 7;          // 128-node buckets (NB <= 1024)

  char* ws = (char*)d_ws;
  size_t off = 0;
  auto alloc = [&](size_t bytes) -> char* {
    char* p = ws + off;
    off = (off + bytes + 255) & ~(size_t)255;
    return p;
  };
  u16*   h1s    = (u16*)  alloc((size_t)N * 64 * 2);
  float* h2s    = (float*)alloc((size_t)N * 16 * 4);
  int*   etmp   = (int*)  alloc((size_t)E * 4);
  int*   degi   = (int*)  alloc((size_t)N * 4);
  float* dinv   = (float*)alloc((size_t)N * 4);
  int*   ccnt   = (int*)  alloc((size_t)(NB + 2) * 4);
  int*   bstart = (int*)  alloc((size_t)(NB + 1) * 4);
  int*   cursor = (int*)  alloc((size_t)NB * 4);
  u16*   W1b    = (u16*)  alloc(8192 * 2);
  float* W2f    = (float*)alloc(1024 * 4);
  float* b1f    = (float*)alloc(64 * 4);
  float* b2f    = (float*)alloc(16 * 4);
  int*   mode   = (int*)  alloc(4);

  hipMemsetAsync(degi, 0, (size_t)N * 4, stream);

  kdetect<<<1, 256, 0, stream>>>((const u16*)W1, 8192, mode);
  kconvw<<<32, 256, 0, stream>>>(W1, b1, W2, b2, mode, W1b, b1f, W2f, b2f);

  kdeg<<<(E / 4 + 255) / 256, 256, 0, stream>>>(dst, degi, E);
  kdinvc<<<(N + 255) / 256, 256, 0, stream>>>(degi, dinv, ccnt, N);
  kscanb<<<1, 1024, 0, stream>>>(ccnt, NB, bstart, cursor);
  kpart<<<(E + 4095) / 4096, 256, 0, stream>>>(src, dst, cursor, etmp, E, NB);

  int tiles = (N + 15) / 16;
  kgemm1<<<(tiles + 3) / 4, 256, 0, stream>>>(x, W1b, mode, dinv, h1s, N);
  kagg1f<<<NB, 512, 0, stream>>>(h1s, etmp, bstart, dinv, b1f, W2f, h2s, N);
  kagg2f<<<NB, 512, 0, stream>>>(h2s, etmp, bstart, dinv, b2f, mode, d_out, N);
}

// Round 6
// 268.920 us; speedup vs baseline: 4.1544x; 4.1544x over previous
//
#include <hip/hip_runtime.h>

// GCN 2-layer forward for MI355X (gfx950).
// Dtype detected on-device (f32 vs bf16 harness conversion).
// Rows pre-scaled by dinv so aggregation is a plain sum.
// CSR build without the scattered-write penalty:
//   kcnt  : bucket (=128 dst nodes) histogram via LDS, few global atomics
//   kscanb: exclusive scan of bucket counts -> bstart, cursor
//   kpart : edges -> etmp packed (src<<7)|dstlow, grouped by bucket
//           (per-block LDS hist -> contiguous runs, write-amp ~1-3x)
//   kfine : per bucket: LDS counting sort by dstlow -> dst-sorted ebuf (writes
//           confined to the bucket's private 8KB range), row_start, dinv
// Aggregation = R3's proven wave-per-node shfl-broadcast gather (8-wide MLP).

typedef unsigned short u16;
typedef __attribute__((ext_vector_type(8))) short short8;   // 8 bf16
typedef __attribute__((ext_vector_type(4))) float f32x4;

__device__ __forceinline__ float bf2f(u16 u) {
  return __uint_as_float(((unsigned int)u) << 16);
}
__device__ __forceinline__ u16 f2bf(float f) {
  unsigned int u = __float_as_uint(f);
  u += 0x7fffu + ((u >> 16) & 1u);
  return (u16)(u >> 16);
}

// ---- dtype detection: bf16-reinterp of f32 data shows huge exponents ----
__global__ __launch_bounds__(256) void kdetect(const u16* __restrict__ w,
                                               int n16, int* __restrict__ mode) {
  __shared__ float red[4];
  float mx = 0.f;
  for (int i = threadIdx.x; i < n16; i += 256) {
    float av = fabsf(bf2f(w[i]));
    if (!(av <= 1e6f)) av = 3e38f;
    mx = fmaxf(mx, av);
  }
  #pragma unroll
  for (int off = 32; off >= 1; off >>= 1) mx = fmaxf(mx, __shfl_xor(mx, off, 64));
  if ((threadIdx.x & 63) == 0) red[threadIdx.x >> 6] = mx;
  __syncthreads();
  if (threadIdx.x == 0) {
    float m2 = fmaxf(fmaxf(red[0], red[1]), fmaxf(red[2], red[3]));
    mode[0] = (m2 > 1e6f) ? 1 : 0;       // 1 = float32 inputs, 0 = bf16
  }
}

__global__ void kconvw(const void* __restrict__ W1r, const void* __restrict__ b1r,
                       const void* __restrict__ W2r, const void* __restrict__ b2r,
                       const int* __restrict__ mode, u16* __restrict__ W1b,
                       float* __restrict__ b1f, float* __restrict__ W2f,
                       float* __restrict__ b2f) {
  int m = mode[0];
  int gid = blockIdx.x * 256 + threadIdx.x, stride = gridDim.x * 256;
  for (int i = gid; i < 8192; i += stride)
    W1b[i] = m ? f2bf(((const float*)W1r)[i]) : ((const u16*)W1r)[i];
  for (int i = gid; i < 1024; i += stride)
    W2f[i] = m ? ((const float*)W2r)[i] : bf2f(((const u16*)W2r)[i]);
  for (int i = gid; i < 64; i += stride)
    b1f[i] = m ? ((const float*)b1r)[i] : bf2f(((const u16*)b1r)[i]);
  for (int i = gid; i < 16; i += stride)
    b2f[i] = m ? ((const float*)b2r)[i] : bf2f(((const u16*)b2r)[i]);
}

// bucket histogram: LDS per block, then one global atomicAdd per (block,bucket)
__global__ __launch_bounds__(256) void kcnt(const int* __restrict__ dst,
                                            int* __restrict__ ccnt, int E, int NB) {
  __shared__ int hist[1024];
  int tid = threadIdx.x;
  for (int i = tid; i < NB; i += 256) hist[i] = 0;
  __syncthreads();
  int e0 = blockIdx.x * 4096 + tid * 16;
  if (e0 + 15 < E) {
    int4 d4[4];
    #pragma unroll
    for (int u = 0; u < 4; ++u) d4[u] = ((const int4*)(dst + e0))[u];
    const int* dp = (const int*)d4;
    #pragma unroll
    for (int k = 0; k < 16; ++k) atomicAdd(&hist[dp[k] >> 7], 1);
  } else {
    for (int k = 0; k < 16; ++k)
      if (e0 + k < E) atomicAdd(&hist[dst[e0 + k] >> 7], 1);
  }
  __syncthreads();
  for (int i = tid; i < NB; i += 256)
    if (hist[i]) atomicAdd(&ccnt[i], hist[i]);
}

// single-block exclusive scan of ccnt[NB] (NB <= 1024) -> bstart, cursor.
__global__ __launch_bounds__(1024) void kscanb(const int* __restrict__ ccnt, int NB,
                                               int* __restrict__ bstart,
                                               int* __restrict__ cursor) {
  __shared__ int wsum[16], wexcl[16];
  int tid = threadIdx.x, lane = tid & 63, wv = tid >> 6;
  int v = (tid < NB) ? ccnt[tid] : 0;
  int s = v;
  #pragma unroll
  for (int off = 1; off < 64; off <<= 1) {
    int t = __shfl_up(s, off, 64);
    if (lane >= off) s += t;
  }
  if (lane == 63) wsum[wv] = s;
  __syncthreads();
  if (tid < 16) {
    int ws = wsum[tid], sc = ws;
    #pragma unroll
    for (int off = 1; off < 16; off <<= 1) {
      int t = __shfl_up(sc, off, 16);
      if (tid >= off) sc += t;
    }
    wexcl[tid] = sc - ws;
  }
  __syncthreads();
  int incl = wexcl[wv] + s;
  if (tid < NB) { bstart[tid] = incl - v; cursor[tid] = incl - v; }
  if (tid == NB - 1) bstart[NB] = incl;   // = E
}

// Partition edges into buckets: etmp[slot] = (src<<7)|(dst&127), grouped by
// bucket = dst>>7. Per-block LDS histogram -> one global atomicAdd per
// (block,bucket) -> contiguous runs.
__global__ __launch_bounds__(256) void kpart(const int* __restrict__ src,
                                             const int* __restrict__ dst,
                                             int* __restrict__ cursor,
                                             int* __restrict__ etmp,
                                             int E, int NB) {
  __shared__ int hist[1024], basep[1024];
  int tid = threadIdx.x;
  for (int i = tid; i < 1024; i += 256) hist[i] = 0;
  __syncthreads();
  int e0 = blockIdx.x * 4096 + tid * 16;
  int pk[16], off[16], cb[16];
  if (e0 + 15 < E) {
    int4 s4[4], d4[4];
    #pragma unroll
    for (int u = 0; u < 4; ++u) {
      s4[u] = ((const int4*)(src + e0))[u];
      d4[u] = ((const int4*)(dst + e0))[u];
    }
    const int* sp = (const int*)s4;
    const int* dp = (const int*)d4;
    #pragma unroll
    for (int k = 0; k < 16; ++k) {
      int s = sp[k], d = dp[k];
      cb[k] = d >> 7;
      pk[k] = (s << 7) | (d & 127);
      off[k] = atomicAdd(&hist[cb[k]], 1);
    }
  } else {
    #pragma unroll
    for (int k = 0; k < 16; ++k) {
      int e = e0 + k;
      cb[k] = -1;
      if (e < E) {
        int s = src[e], d = dst[e];
        cb[k] = d >> 7;
        pk[k] = (s << 7) | (d & 127);
        off[k] = atomicAdd(&hist[cb[k]], 1);
      }
    }
  }
  __syncthreads();
  for (int i = tid; i < NB; i += 256)
    if (hist[i]) basep[i] = atomicAdd(&cursor[i], hist[i]);
  __syncthreads();
  if (e0 + 15 < E) {
    #pragma unroll
    for (int k = 0; k < 16; ++k) etmp[basep[cb[k]] + off[k]] = pk[k];
  } else {
    #pragma unroll
    for (int k = 0; k < 16; ++k)
      if (cb[k] >= 0) etmp[basep[cb[k]] + off[k]] = pk[k];
  }
}

// Per bucket: counting sort by dst_low in LDS; emit dst-sorted ebuf (writes
// stay inside the bucket's private range), row_start, dinv.
__global__ __launch_bounds__(256) void kfine(const int* __restrict__ etmp,
                                             const int* __restrict__ bstart,
                                             int* __restrict__ ebuf,
                                             int* __restrict__ row_start,
                                             float* __restrict__ dinv,
                                             int N, int E) {
  __shared__ int hist[128], curs[128];
  int bk = blockIdx.x, tid = threadIdx.x;
  int beg = bstart[bk], end = bstart[bk + 1];
  if (tid < 128) hist[tid] = 0;
  __syncthreads();
  for (int i = beg + tid; i < end; i += 256)
    atomicAdd(&hist[etmp[i] & 127], 1);
  __syncthreads();
  if (tid < 64) {
    int v0 = hist[tid], v1 = hist[tid + 64];
    int s0 = v0;
    #pragma unroll
    for (int off = 1; off < 64; off <<= 1) {
      int t = __shfl_up(s0, off, 64);
      if (tid >= off) s0 += t;
    }
    int tot0 = __shfl(s0, 63, 64);
    int s1 = v1;
    #pragma unroll
    for (int off = 1; off < 64; off <<= 1) {
      int t = __shfl_up(s1, off, 64);
      if (tid >= off) s1 += t;
    }
    s1 += tot0;
    int e0x = s0 - v0, e1x = s1 - v1;
    int node0 = (bk << 7) + tid, node1 = node0 + 64;
    if (node0 < N) {
      row_start[node0] = beg + e0x;
      dinv[node0] = rsqrtf((float)(v0 + 1));
    }
    if (node1 < N) {
      row_start[node1] = beg + e1x;
      dinv[node1] = rsqrtf((float)(v1 + 1));
    }
    curs[tid] = e0x;
    curs[tid + 64] = e1x;
  }
  __syncthreads();
  for (int i = beg + tid; i < end; i += 256) {
    int pk = etmp[i];
    int pos = atomicAdd(&curs[pk & 127], 1);
    ebuf[beg + pos] = pk >> 7;
  }
  if (bk == 0 && tid == 0) row_start[N] = E;
}

// h1s = (x @ W1) * dinv[row], bf16 out. One wave per 16-row tile.
__global__ __launch_bounds__(256) void kgemm1(const void* __restrict__ xraw,
                                              const u16* __restrict__ W1b,
                                              const int* __restrict__ mode,
                                              const float* __restrict__ dinv,
                                              u16* __restrict__ h1s, int n) {
  int mflag = mode[0];
  int wid = blockIdx.x * 4 + (threadIdx.x >> 6);
  int row0 = wid * 16;
  if (row0 >= n) return;
  int lane = threadIdx.x & 63;
  int m = lane & 15, q = lane >> 4;

  short8 bfrag[4][4];
  for (int jb = 0; jb < 4; ++jb)
    for (int kb = 0; kb < 4; ++kb) {
      short8 f;
      #pragma unroll
      for (int j = 0; j < 8; ++j)
        f[j] = (short)W1b[(kb * 32 + q * 8 + j) * 64 + jb * 16 + m];
      bfrag[jb][kb] = f;
    }

  f32x4 acc[4];
  #pragma unroll
  for (int jb = 0; jb < 4; ++jb) acc[jb] = (f32x4){0.f, 0.f, 0.f, 0.f};

  #pragma unroll
  for (int kb = 0; kb < 4; ++kb) {
    short8 a;
    if (mflag) {
      const float* xf = (const float*)xraw + (size_t)(row0 + m) * 128 + kb * 32 + q * 8;
      float4 u0 = ((const float4*)xf)[0];
      float4 u1 = ((const float4*)xf)[1];
      a[0] = (short)f2bf(u0.x); a[1] = (short)f2bf(u0.y);
      a[2] = (short)f2bf(u0.z); a[3] = (short)f2bf(u0.w);
      a[4] = (short)f2bf(u1.x); a[5] = (short)f2bf(u1.y);
      a[6] = (short)f2bf(u1.z); a[7] = (short)f2bf(u1.w);
    } else {
      a = *(const short8*)((const u16*)xraw + (size_t)(row0 + m) * 128 + kb * 32 + q * 8);
    }
    #pragma unroll
    for (int jb = 0; jb < 4; ++jb)
      acc[jb] = __builtin_amdgcn_mfma_f32_16x16x32_bf16(a, bfrag[jb][kb], acc[jb], 0, 0, 0);
  }

  #pragma unroll
  for (int r = 0; r < 4; ++r) {
    float dv = dinv[row0 + q * 4 + r];
    #pragma unroll
    for (int jb = 0; jb < 4; ++jb)
      h1s[(row0 + q * 4 + r) * 64 + jb * 16 + m] = f2bf(acc[jb][r] * dv);
  }
}

// Layer-1 aggregate (plain sum) + relu + fused GEMM2. One wave per node.
__global__ __launch_bounds__(256) void kagg1(
    const u16* __restrict__ h1s, const int* __restrict__ ebuf,
    const int* __restrict__ row_start, const float* __restrict__ dinv,
    const float* __restrict__ b1f, const float* __restrict__ W2f,
    float* __restrict__ h2s, int n) {
  __shared__ float W2s[64 * 17];
  __shared__ float rows[4][64];
  int tid = threadIdx.x;
  for (int i = tid; i < 1024; i += 256)
    W2s[(i >> 4) * 17 + (i & 15)] = W2f[i];
  __syncthreads();

  int lane = tid & 63, wv = tid >> 6;
  int node = blockIdx.x * 4 + wv;
  if (node >= n) node = n - 1;            // clamp: recompute is benign
  int beg = row_start[node], end = row_start[node + 1];
  float self = bf2f(h1s[node * 64 + lane]);
  float acc = 0.f;
  for (int base = beg; base < end; base += 64) {
    int idx = base + lane;
    int eidx = ebuf[(idx < end) ? idx : beg];
    int cnt = min(64, end - base);
    int k = 0;
    for (; k + 8 <= cnt; k += 8) {
      int s0 = __shfl(eidx, k, 64),     s1 = __shfl(eidx, k + 1, 64);
      int s2 = __shfl(eidx, k + 2, 64), s3 = __shfl(eidx, k + 3, 64);
      int s4 = __shfl(eidx, k + 4, 64), s5 = __shfl(eidx, k + 5, 64);
      int s6 = __shfl(eidx, k + 6, 64), s7 = __shfl(eidx, k + 7, 64);
      float g0 = bf2f(h1s[s0 * 64 + lane]), g1 = bf2f(h1s[s1 * 64 + lane]);
      float g2 = bf2f(h1s[s2 * 64 + lane]), g3 = bf2f(h1s[s3 * 64 + lane]);
      float g4 = bf2f(h1s[s4 * 64 + lane]), g5 = bf2f(h1s[s5 * 64 + lane]);
      float g6 = bf2f(h1s[s6 * 64 + lane]), g7 = bf2f(h1s[s7 * 64 + lane]);
      acc += ((g0 + g1) + (g2 + g3)) + ((g4 + g5) + (g6 + g7));
    }
    for (; k < cnt; ++k) {
      int s0 = __shfl(eidx, k, 64);
      acc += bf2f(h1s[s0 * 64 + lane]);
    }
  }
  float v = dinv[node] * (acc + self) + b1f[lane];
  v = fmaxf(v, 0.f);
  rows[wv][lane] = v;
  __syncthreads();

  int c = lane & 15, g = lane >> 4;
  float p = 0.f;
  #pragma unroll
  for (int j0 = 0; j0 < 16; ++j0) {
    int j = g * 16 + j0;
    p = fmaf(rows[wv][j], W2s[j * 17 + c], p);
  }
  p += __shfl_xor(p, 16, 64);
  p += __shfl_xor(p, 32, 64);
  if (g == 0) h2s[node * 16 + c] = p * dinv[node];
}

// Layer-2 aggregate + bias + relu + log_softmax. Quarter-wave per node.
__global__ __launch_bounds__(256) void kagg2(
    const float* __restrict__ h2s, const int* __restrict__ ebuf,
    const int* __restrict__ row_start, const float* __restrict__ dinv,
    const float* __restrict__ b2f, const int* __restrict__ mode,
    void* __restrict__ out, int n) {
  int mflag = mode[0];
  int tid = threadIdx.x;
  int lane = tid & 63, wv = tid >> 6;
  int c = lane & 15, sub = lane >> 4;
  int node = blockIdx.x * 16 + wv * 4 + sub;
  if (node >= n) node = n - 1;            // clamp: recompute is benign
  int beg = row_start[node], end = row_start[node + 1];
  float self = h2s[node * 16 + c];
  float acc = 0.f;
  for (int base = beg; base < end; base += 16) {
    int idx = base + c;
    int eidx = ebuf[(idx < end) ? idx : beg];
    int cnt = min(16, end - base);
    int k = 0;
    for (; k + 8 <= cnt; k += 8) {
      int s0 = __shfl(eidx, k, 16),     s1 = __shfl(eidx, k + 1, 16);
      int s2 = __shfl(eidx, k + 2, 16), s3 = __shfl(eidx, k + 3, 16);
      int s4 = __shfl(eidx, k + 4, 16), s5 = __shfl(eidx, k + 5, 16);
      int s6 = __shfl(eidx, k + 6, 16), s7 = __shfl(eidx, k + 7, 16);
      float g0 = h2s[s0 * 16 + c], g1 = h2s[s1 * 16 + c];
      float g2 = h2s[s2 * 16 + c], g3 = h2s[s3 * 16 + c];
      float g4 = h2s[s4 * 16 + c], g5 = h2s[s5 * 16 + c];
      float g6 = h2s[s6 * 16 + c], g7 = h2s[s7 * 16 + c];
      acc += ((g0 + g1) + (g2 + g3)) + ((g4 + g5) + (g6 + g7));
    }
    for (; k < cnt; ++k) {
      int s0 = __shfl(eidx, k, 16);
      acc += h2s[s0 * 16 + c];
    }
  }
  float v = dinv[node] * (acc + self) + b2f[c];
  v = fmaxf(v, 0.f);

  float m = v;
  #pragma unroll
  for (int off = 8; off >= 1; off >>= 1) m = fmaxf(m, __shfl_xor(m, off, 16));
  float ex = __expf(v - m);
  float s = ex;
  #pragma unroll
  for (int off = 8; off >= 1; off >>= 1) s += __shfl_xor(s, off, 16);
  float r = v - m - __logf(s);
  size_t oidx = (size_t)node * 16 + c;
  if (mflag) ((float*)out)[oidx] = r;
  else       ((u16*)out)[oidx] = f2bf(r);
}

extern "C" void kernel_launch(void* const* d_in, const int* in_sizes, int n_in,
                              void* d_out, int out_size, void* d_ws, size_t ws_size,
                              hipStream_t stream) {
  const void* x  = d_in[0];
  const int* ei  = (const int*)d_in[1];
  const void* W1 = d_in[2];
  const void* b1 = d_in[3];
  const void* W2 = d_in[4];
  const void* b2 = d_in[5];

  const int N = in_sizes[0] / 128;
  const int E = in_sizes[1] / 2;
  const int* src = ei;
  const int* dst = ei + E;
  const int NB = (N + 127) >> 7;          // 128-node buckets (NB <= 1024)

  char* ws = (char*)d_ws;
  size_t off = 0;
  auto alloc = [&](size_t bytes) -> char* {
    char* p = ws + off;
    off = (off + bytes + 255) & ~(size_t)255;
    return p;
  };
  u16*   h1s       = (u16*)  alloc((size_t)N * 64 * 2);
  float* h2s       = (float*)alloc((size_t)N * 16 * 4);
  int*   etmp      = (int*)  alloc((size_t)E * 4);
  int*   ebuf      = (int*)  alloc((size_t)E * 4);
  float* dinv      = (float*)alloc((size_t)N * 4);
  int*   row_start = (int*)  alloc((size_t)(N + 1) * 4);
  int*   ccnt      = (int*)  alloc((size_t)(NB + 1) * 4);
  int*   bstart    = (int*)  alloc((size_t)(NB + 1) * 4);
  int*   cursor    = (int*)  alloc((size_t)NB * 4);
  u16*   W1b       = (u16*)  alloc(8192 * 2);
  float* W2f       = (float*)alloc(1024 * 4);
  float* b1f       = (float*)alloc(64 * 4);
  float* b2f       = (float*)alloc(16 * 4);
  int*   mode      = (int*)  alloc(4);

  hipMemsetAsync(ccnt, 0, (size_t)(NB + 1) * 4, stream);

  kdetect<<<1, 256, 0, stream>>>((const u16*)W1, 8192, mode);
  kconvw<<<32, 256, 0, stream>>>(W1, b1, W2, b2, mode, W1b, b1f, W2f, b2f);

  int pblocks = (E + 4095) / 4096;
  kcnt<<<pblocks, 256, 0, stream>>>(dst, ccnt, E, NB);
  kscanb<<<1, 1024, 0, stream>>>(ccnt, NB, bstart, cursor);
  kpart<<<pblocks, 256, 0, stream>>>(src, dst, cursor, etmp, E, NB);
  kfine<<<NB, 256, 0, stream>>>(etmp, bstart, ebuf, row_start, dinv, N, E);

  int tiles = (N + 15) / 16;
  kgemm1<<<(tiles + 3) / 4, 256, 0, stream>>>(x, W1b, mode, dinv, h1s, N);
  kagg1<<<(N + 3) / 4, 256, 0, stream>>>(h1s, ebuf, row_start, dinv, b1f, W2f, h2s, N);
  kagg2<<<(N + 15) / 16, 256, 0, stream>>>(h2s, ebuf, row_start, dinv, b2f, mode, d_out, N);
}

// Round 7
// 252.872 us; speedup vs baseline: 4.4181x; 1.0635x over previous
//
#include <hip/hip_runtime.h>

// GCN 2-layer forward for MI355X (gfx950).
// Dtype detected on-device (f32 vs bf16 harness conversion), inside kconvw.
// Rows pre-scaled by dinv so aggregation is a plain sum.
// CSR build with padded buckets (no count pass, no scan):
//   kpart : edges -> etmp[bk*CAP + slot] packed (src<<7)|dstlow; per-block LDS
//           hist -> one global atomicAdd per (block,bucket) -> contiguous runs
//   kfine : per bucket: stage packed edges in LDS, counting-sort by dstlow,
//           write back dst-sorted in place; emit rowse (beg,end) + dinv
// Aggregation: wave-per-node, dword gathers (2 bf16 features/lane):
//   kagg1 : half-wave per edge (2 edges/load-instr) + fused GEMM2 -> h2s bf16
//   kagg2 : oct per edge (8 edges/load-instr) + log_softmax -> out

typedef unsigned short u16;
typedef __attribute__((ext_vector_type(8))) short short8;   // 8 bf16
typedef __attribute__((ext_vector_type(4))) float f32x4;

#define CAP 4096   // bucket capacity: Binomial(1.6M, 1/782) ~ 2046 +- 45; 45 sigma

__device__ __forceinline__ float bf2f(u16 u) {
  return __uint_as_float(((unsigned int)u) << 16);
}
__device__ __forceinline__ u16 f2bf(float f) {
  unsigned int u = __float_as_uint(f);
  u += 0x7fffu + ((u >> 16) & 1u);
  return (u16)(u >> 16);
}

// ---- weight canonicalization + integrated dtype detect ----
// bf16-reinterp of f32 data shows huge exponents in the low halves.
__global__ __launch_bounds__(256) void kconvw(const void* __restrict__ W1r,
                                              const void* __restrict__ b1r,
                                              const void* __restrict__ W2r,
                                              const void* __restrict__ b2r,
                                              u16* __restrict__ W1b,
                                              float* __restrict__ b1f,
                                              float* __restrict__ W2f,
                                              float* __restrict__ b2f,
                                              int* __restrict__ mode) {
  __shared__ float red[4];
  __shared__ int smode;
  const u16* w = (const u16*)W1r;
  float mx = 0.f;
  for (int i = threadIdx.x; i < 8192; i += 256) {   // first 8192 u16 of W1
    float av = fabsf(bf2f(w[i]));
    if (!(av <= 1e6f)) av = 3e38f;
    mx = fmaxf(mx, av);
  }
  #pragma unroll
  for (int off = 32; off >= 1; off >>= 1) mx = fmaxf(mx, __shfl_xor(mx, off, 64));
  if ((threadIdx.x & 63) == 0) red[threadIdx.x >> 6] = mx;
  __syncthreads();
  if (threadIdx.x == 0) {
    float m2 = fmaxf(fmaxf(red[0], red[1]), fmaxf(red[2], red[3]));
    smode = (m2 > 1e6f) ? 1 : 0;
    if (blockIdx.x == 0) mode[0] = smode;   // for kgemm1 / kagg2
  }
  __syncthreads();
  int m = smode;
  int gid = blockIdx.x * 256 + threadIdx.x, stride = gridDim.x * 256;
  for (int i = gid; i < 8192; i += stride)
    W1b[i] = m ? f2bf(((const float*)W1r)[i]) : ((const u16*)W1r)[i];
  for (int i = gid; i < 1024; i += stride)
    W2f[i] = m ? ((const float*)W2r)[i] : bf2f(((const u16*)W2r)[i]);
  for (int i = gid; i < 64; i += stride)
    b1f[i] = m ? ((const float*)b1r)[i] : bf2f(((const u16*)b1r)[i]);
  for (int i = gid; i < 16; i += stride)
    b2f[i] = m ? ((const float*)b2r)[i] : bf2f(((const u16*)b2r)[i]);
}

// Partition edges into padded buckets: etmp[bk*CAP + slot] = (src<<7)|(dst&127).
// Per-block LDS histogram -> one global atomicAdd per (block,bucket).
__global__ __launch_bounds__(256) void kpart(const int* __restrict__ src,
                                             const int* __restrict__ dst,
                                             int* __restrict__ cursor,
                                             int* __restrict__ etmp,
                                             int E, int NB) {
  __shared__ int hist[1024], basep[1024];
  int tid = threadIdx.x;
  for (int i = tid; i < 1024; i += 256) hist[i] = 0;
  __syncthreads();
  int e0 = blockIdx.x * 4096 + tid * 16;
  int pk[16], off[16], cb[16];
  if (e0 + 15 < E) {
    int4 s4[4], d4[4];
    #pragma unroll
    for (int u = 0; u < 4; ++u) {
      s4[u] = ((const int4*)(src + e0))[u];
      d4[u] = ((const int4*)(dst + e0))[u];
    }
    const int* sp = (const int*)s4;
    const int* dp = (const int*)d4;
    #pragma unroll
    for (int k = 0; k < 16; ++k) {
      int s = sp[k], d = dp[k];
      cb[k] = d >> 7;
      pk[k] = (s << 7) | (d & 127);
      off[k] = atomicAdd(&hist[cb[k]], 1);
    }
  } else {
    #pragma unroll
    for (int k = 0; k < 16; ++k) {
      int e = e0 + k;
      cb[k] = -1;
      if (e < E) {
        int s = src[e], d = dst[e];
        cb[k] = d >> 7;
        pk[k] = (s << 7) | (d & 127);
        off[k] = atomicAdd(&hist[cb[k]], 1);
      }
    }
  }
  __syncthreads();
  for (int i = tid; i < NB; i += 256)
    if (hist[i]) basep[i] = atomicAdd(&cursor[i], hist[i]);
  __syncthreads();
  if (e0 + 15 < E) {
    #pragma unroll
    for (int k = 0; k < 16; ++k)
      etmp[cb[k] * CAP + basep[cb[k]] + off[k]] = pk[k];
  } else {
    #pragma unroll
    for (int k = 0; k < 16; ++k)
      if (cb[k] >= 0) etmp[cb[k] * CAP + basep[cb[k]] + off[k]] = pk[k];
  }
}

// Per bucket: LDS-staged counting sort by dst_low; write back src indices
// dst-sorted IN PLACE; emit rowse = (beg,end) per node and dinv.
__global__ __launch_bounds__(256) void kfine(int* __restrict__ etmp,
                                             const int* __restrict__ cursor,
                                             int2* __restrict__ rowse,
                                             float* __restrict__ dinv, int N) {
  __shared__ int eL[CAP];
  __shared__ int hist[128], curs[128];
  int bk = blockIdx.x, tid = threadIdx.x;
  int cnt = cursor[bk];
  int base = bk * CAP;
  if (tid < 128) hist[tid] = 0;
  __syncthreads();
  for (int i = tid; i < cnt; i += 256) {
    int pk = etmp[base + i];
    eL[i] = pk;
    atomicAdd(&hist[pk & 127], 1);
  }
  __syncthreads();
  if (tid < 64) {
    int v0 = hist[tid], v1 = hist[tid + 64];
    int s0 = v0;
    #pragma unroll
    for (int off = 1; off < 64; off <<= 1) {
      int t = __shfl_up(s0, off, 64);
      if (tid >= off) s0 += t;
    }
    int tot0 = __shfl(s0, 63, 64);
    int s1 = v1;
    #pragma unroll
    for (int off = 1; off < 64; off <<= 1) {
      int t = __shfl_up(s1, off, 64);
      if (tid >= off) s1 += t;
    }
    s1 += tot0;
    int e0x = s0 - v0, e1x = s1 - v1;
    int node0 = (bk << 7) + tid, node1 = node0 + 64;
    if (node0 < N) {
      rowse[node0] = make_int2(base + e0x, base + e0x + v0);
      dinv[node0] = rsqrtf((float)(v0 + 1));
    }
    if (node1 < N) {
      rowse[node1] = make_int2(base + e1x, base + e1x + v1);
      dinv[node1] = rsqrtf((float)(v1 + 1));
    }
    curs[tid] = e0x;
    curs[tid + 64] = e1x;
  }
  __syncthreads();
  for (int i = tid; i < cnt; i += 256) {
    int pk = eL[i];
    int pos = atomicAdd(&curs[pk & 127], 1);
    etmp[base + pos] = pk >> 7;          // now holds sorted src index
  }
}

// h1s = (x @ W1) * dinv[row], bf16 out. One wave per 16-row tile.
// A frag: A[m=lane&15][k=quad*8+j]; C/D: col=lane&15, row=quad*4+reg.
__global__ __launch_bounds__(256) void kgemm1(const void* __restrict__ xraw,
                                              const u16* __restrict__ W1b,
                                              const int* __restrict__ mode,
                                              const float* __restrict__ dinv,
                                              u16* __restrict__ h1s, int n) {
  int mflag = mode[0];
  int wid = blockIdx.x * 4 + (threadIdx.x >> 6);
  int row0 = wid * 16;
  if (row0 >= n) return;
  int lane = threadIdx.x & 63;
  int m = lane & 15, q = lane >> 4;

  short8 bfrag[4][4];
  for (int jb = 0; jb < 4; ++jb)
    for (int kb = 0; kb < 4; ++kb) {
      short8 f;
      #pragma unroll
      for (int j = 0; j < 8; ++j)
        f[j] = (short)W1b[(kb * 32 + q * 8 + j) * 64 + jb * 16 + m];
      bfrag[jb][kb] = f;
    }

  f32x4 acc[4];
  #pragma unroll
  for (int jb = 0; jb < 4; ++jb) acc[jb] = (f32x4){0.f, 0.f, 0.f, 0.f};

  #pragma unroll
  for (int kb = 0; kb < 4; ++kb) {
    short8 a;
    if (mflag) {
      const float* xf = (const float*)xraw + (size_t)(row0 + m) * 128 + kb * 32 + q * 8;
      float4 u0 = ((const float4*)xf)[0];
      float4 u1 = ((const float4*)xf)[1];
      a[0] = (short)f2bf(u0.x); a[1] = (short)f2bf(u0.y);
      a[2] = (short)f2bf(u0.z); a[3] = (short)f2bf(u0.w);
      a[4] = (short)f2bf(u1.x); a[5] = (short)f2bf(u1.y);
      a[6] = (short)f2bf(u1.z); a[7] = (short)f2bf(u1.w);
    } else {
      a = *(const short8*)((const u16*)xraw + (size_t)(row0 + m) * 128 + kb * 32 + q * 8);
    }
    #pragma unroll
    for (int jb = 0; jb < 4; ++jb)
      acc[jb] = __builtin_amdgcn_mfma_f32_16x16x32_bf16(a, bfrag[jb][kb], acc[jb], 0, 0, 0);
  }

  #pragma unroll
  for (int r = 0; r < 4; ++r) {
    float dv = dinv[row0 + q * 4 + r];
    #pragma unroll
    for (int jb = 0; jb < 4; ++jb)
      h1s[(row0 + q * 4 + r) * 64 + jb * 16 + m] = f2bf(acc[jb][r] * dv);
  }
}

// Layer-1 aggregate + relu + fused GEMM2 -> h2s (bf16). One wave per node.
// Lane = dword (2 bf16 features, fl=lane&31); half-wave 0/1 take even/odd
// edges -> 2 edges per load instruction; halves combined via shfl_xor(32).
__global__ __launch_bounds__(256) void kagg1(
    const u16* __restrict__ h1s, const int* __restrict__ esort,
    const int2* __restrict__ rowse, const float* __restrict__ dinv,
    const float* __restrict__ b1f, const float* __restrict__ W2f,
    u16* __restrict__ h2sb, int n) {
  __shared__ float W2s[64 * 17];
  __shared__ float rows[4][64];
  int tid = threadIdx.x;
  for (int i = tid; i < 1024; i += 256)
    W2s[(i >> 4) * 17 + (i & 15)] = W2f[i];
  __syncthreads();

  int lane = tid & 63, wv = tid >> 6;
  int node = blockIdx.x * 4 + wv;
  if (node >= n) node = n - 1;
  int2 se = rowse[node];
  int beg = se.x, end = se.y;
  int fl = lane & 31, half = lane >> 5;
  const unsigned int* h1s32 = (const unsigned int*)h1s;   // 32 dwords/row
  unsigned int selfg = h1s32[node * 32 + fl];
  float ax = 0.f, ay = 0.f;
  for (int base = beg; base < end; base += 64) {
    int idx = base + lane;
    int eidx = esort[(idx < end) ? idx : (end - 1)];      // coalesced 64-wide
    int cnt = min(64, end - base);
    int k = 0;
    for (; k + 16 <= cnt; k += 16) {      // 8 pairs = 16 edges, 8 loads in flight
      unsigned int g[8];
      #pragma unroll
      for (int p = 0; p < 8; ++p) {
        int s = __shfl(eidx, k + 2 * p + half, 64);
        g[p] = h1s32[s * 32 + fl];
      }
      #pragma unroll
      for (int p = 0; p < 8; ++p) {
        ax += bf2f((u16)(g[p] & 0xffff));
        ay += bf2f((u16)(g[p] >> 16));
      }
    }
    for (; k + 2 <= cnt; k += 2) {
      int s = __shfl(eidx, k + half, 64);
      unsigned int g = h1s32[s * 32 + fl];
      ax += bf2f((u16)(g & 0xffff));
      ay += bf2f((u16)(g >> 16));
    }
    if (k < cnt) {
      int s = __shfl(eidx, k, 64);
      if (half == 0) {
        unsigned int g = h1s32[s * 32 + fl];
        ax += bf2f((u16)(g & 0xffff));
        ay += bf2f((u16)(g >> 16));
      }
    }
  }
  // combine halves (all lanes end with the full sums for their feature pair)
  ax += __shfl_xor(ax, 32, 64);
  ay += __shfl_xor(ay, 32, 64);
  float dv = dinv[node];
  float2 b1v = ((const float2*)b1f)[fl];
  float vx = fmaxf(dv * (ax + bf2f((u16)(selfg & 0xffff))) + b1v.x, 0.f);
  float vy = fmaxf(dv * (ay + bf2f((u16)(selfg >> 16))) + b1v.y, 0.f);
  if (half == 0) ((float2*)rows[wv])[fl] = make_float2(vx, vy);
  __syncthreads();

  // GEMM2: h2[c] = sum_j rows[j]*W2[j][c]; lane -> (c=lane&15, g=lane>>4)
  int c = lane & 15, g = lane >> 4;
  float p = 0.f;
  #pragma unroll
  for (int j0 = 0; j0 < 16; ++j0) {
    int j = g * 16 + j0;
    p = fmaf(rows[wv][j], W2s[j * 17 + c], p);
  }
  p += __shfl_xor(p, 16, 64);
  p += __shfl_xor(p, 32, 64);
  if (g == 0) h2sb[node * 16 + c] = f2bf(p * dv);
}

// Layer-2 aggregate + bias + relu + log_softmax. One wave per node.
// h2s row = 16 bf16 = 8 dwords; oct (lane>>3) per edge -> 8 edges/load-instr.
__global__ __launch_bounds__(256) void kagg2(
    const u16* __restrict__ h2sb, const int* __restrict__ esort,
    const int2* __restrict__ rowse, const float* __restrict__ dinv,
    const float* __restrict__ b2f, const int* __restrict__ mode,
    void* __restrict__ out, int n) {
  int mflag = mode[0];
  int tid = threadIdx.x;
  int lane = tid & 63, wv = tid >> 6;
  int node = blockIdx.x * 4 + wv;
  if (node >= n) node = n - 1;
  int2 se = rowse[node];
  int beg = se.x, end = se.y;
  int fl = lane & 7, oct = lane >> 3;
  const unsigned int* h2s32 = (const unsigned int*)h2sb;   // 8 dwords/row
  unsigned int selfg = h2s32[node * 8 + fl];
  float ax = 0.f, ay = 0.f;
  for (int base = beg; base < end; base += 64) {
    int idx = base + lane;
    int eidx = esort[(idx < end) ? idx : (end - 1)];
    int cnt = min(64, end - base);
    int k = 0;
    for (; k + 16 <= cnt; k += 16) {      // 2x8 edges, 2 loads in flight
      int s0 = __shfl(eidx, k + oct, 64);
      int s1 = __shfl(eidx, k + 8 + oct, 64);
      unsigned int g0 = h2s32[s0 * 8 + fl];
      unsigned int g1 = h2s32[s1 * 8 + fl];
      ax += bf2f((u16)(g0 & 0xffff)) + bf2f((u16)(g1 & 0xffff));
      ay += bf2f((u16)(g0 >> 16)) + bf2f((u16)(g1 >> 16));
    }
    for (; k + 8 <= cnt; k += 8) {
      int s = __shfl(eidx, k + oct, 64);
      unsigned int g = h2s32[s * 8 + fl];
      ax += bf2f((u16)(g & 0xffff));
      ay += bf2f((u16)(g >> 16));
    }
    if (k < cnt) {
      int r = cnt - k;
      int s = __shfl(eidx, k + ((oct < r) ? oct : 0), 64);
      if (oct < r) {
        unsigned int g = h2s32[s * 8 + fl];
        ax += bf2f((u16)(g & 0xffff));
        ay += bf2f((u16)(g >> 16));
      }
    }
  }
  // combine 8 octs
  #pragma unroll
  for (int off = 8; off <= 32; off <<= 1) {
    ax += __shfl_xor(ax, off, 64);
    ay += __shfl_xor(ay, off, 64);
  }
  float dv = dinv[node];
  float2 b2v = ((const float2*)b2f)[fl];
  float vx = fmaxf(dv * (ax + bf2f((u16)(selfg & 0xffff))) + b2v.x, 0.f);
  float vy = fmaxf(dv * (ay + bf2f((u16)(selfg >> 16))) + b2v.y, 0.f);

  float m = fmaxf(vx, vy);
  #pragma unroll
  for (int off = 1; off <= 4; off <<= 1) m = fmaxf(m, __shfl_xor(m, off, 8));
  float ex = __expf(vx - m) + __expf(vy - m);
  #pragma unroll
  for (int off = 1; off <= 4; off <<= 1) ex += __shfl_xor(ex, off, 8);
  float lg = __logf(ex);
  float rx = vx - m - lg, ry = vy - m - lg;
  if (lane < 8) {
    if (mflag) ((float2*)out)[(size_t)node * 8 + fl] = make_float2(rx, ry);
    else ((unsigned int*)out)[(size_t)node * 8 + fl] =
           (unsigned int)f2bf(rx) | ((unsigned int)f2bf(ry) << 16);
  }
}

extern "C" void kernel_launch(void* const* d_in, const int* in_sizes, int n_in,
                              void* d_out, int out_size, void* d_ws, size_t ws_size,
                              hipStream_t stream) {
  const void* x  = d_in[0];
  const int* ei  = (const int*)d_in[1];
  const void* W1 = d_in[2];
  const void* b1 = d_in[3];
  const void* W2 = d_in[4];
  const void* b2 = d_in[5];

  const int N = in_sizes[0] / 128;
  const int E = in_sizes[1] / 2;
  const int* src = ei;
  const int* dst = ei + E;
  const int NB = (N + 127) >> 7;          // 128-node buckets

  char* ws = (char*)d_ws;
  size_t off = 0;
  auto alloc = [&](size_t bytes) -> char* {
    char* p = ws + off;
    off = (off + bytes + 255) & ~(size_t)255;
    return p;
  };
  u16*   h1s    = (u16*)  alloc((size_t)N * 64 * 2);
  u16*   h2sb   = (u16*)  alloc((size_t)N * 16 * 2);
  int*   etmp   = (int*)  alloc((size_t)NB * CAP * 4);   // packed, then sorted src
  float* dinv   = (float*)alloc((size_t)N * 4);
  int2*  rowse  = (int2*) alloc((size_t)N * 8);
  int*   cursor = (int*)  alloc((size_t)NB * 4);
  u16*   W1b    = (u16*)  alloc(8192 * 2);
  float* W2f    = (float*)alloc(1024 * 4);
  float* b1f    = (float*)alloc(64 * 4);
  float* b2f    = (float*)alloc(16 * 4);
  int*   mode   = (int*)  alloc(4);

  hipMemsetAsync(cursor, 0, (size_t)NB * 4, stream);

  kconvw<<<32, 256, 0, stream>>>(W1, b1, W2, b2, W1b, b1f, W2f, b2f, mode);

  kpart<<<(E + 4095) / 4096, 256, 0, stream>>>(src, dst, cursor, etmp, E, NB);
  kfine<<<NB, 256, 0, stream>>>(etmp, cursor, rowse, dinv, N);

  int tiles = (N + 15) / 16;
  kgemm1<<<(tiles + 3) / 4, 256, 0, stream>>>(x, W1b, mode, dinv, h1s, N);
  kagg1<<<(N + 3) / 4, 256, 0, stream>>>(h1s, etmp, rowse, dinv, b1f, W2f, h2sb, N);
  kagg2<<<(N + 3) / 4, 256, 0, stream>>>(h2sb, etmp, rowse, dinv, b2f, mode, d_out, N);
}

// Round 8
// 219.482 us; speedup vs baseline: 5.0902x; 1.1521x over previous
//
#include <hip/hip_runtime.h>

// GCN 2-layer forward for MI355X (gfx950).
// Dtype detected on-device (f32 vs bf16 harness conversion), inside kconvw.
// Rows pre-scaled by dinv so aggregation is a plain sum.
// CSR build with padded buckets (no count pass, no scan):
//   kpart : edges -> etmp[bk*CAP+slot] packed (src<<7)|dstlow (512 thr/block)
//   kfine : per bucket: LDS counting sort by dstlow, in-place; rowse + dinv
// Aggregation (fixed-overhead-minimized; avg deg = 16):
//   kagg1 : QUARTER-wave per node; lane owns 4 features (uint2 slice) so no
//           cross-lane combine; width-16 shfl GEMM2 epilogue -> h2sb bf16
//   kagg2 : OCT per node; lane owns 2 classes; width-8 softmax -> out

typedef unsigned short u16;
typedef __attribute__((ext_vector_type(8))) short short8;   // 8 bf16
typedef __attribute__((ext_vector_type(4))) float f32x4;

#define CAP 4096   // bucket capacity: Binomial(1.6M, 1/782) ~ 2046 +- 45

__device__ __forceinline__ float bf2f(u16 u) {
  return __uint_as_float(((unsigned int)u) << 16);
}
__device__ __forceinline__ u16 f2bf(float f) {
  unsigned int u = __float_as_uint(f);
  u += 0x7fffu + ((u >> 16) & 1u);
  return (u16)(u >> 16);
}

// ---- weight canonicalization + integrated dtype detect ----
__global__ __launch_bounds__(256) void kconvw(const void* __restrict__ W1r,
                                              const void* __restrict__ b1r,
                                              const void* __restrict__ W2r,
                                              const void* __restrict__ b2r,
                                              u16* __restrict__ W1b,
                                              float* __restrict__ b1f,
                                              float* __restrict__ W2f,
                                              float* __restrict__ b2f,
                                              int* __restrict__ mode) {
  __shared__ float red[4];
  __shared__ int smode;
  const u16* w = (const u16*)W1r;
  float mx = 0.f;
  for (int i = threadIdx.x; i < 8192; i += 256) {
    float av = fabsf(bf2f(w[i]));
    if (!(av <= 1e6f)) av = 3e38f;
    mx = fmaxf(mx, av);
  }
  #pragma unroll
  for (int off = 32; off >= 1; off >>= 1) mx = fmaxf(mx, __shfl_xor(mx, off, 64));
  if ((threadIdx.x & 63) == 0) red[threadIdx.x >> 6] = mx;
  __syncthreads();
  if (threadIdx.x == 0) {
    float m2 = fmaxf(fmaxf(red[0], red[1]), fmaxf(red[2], red[3]));
    smode = (m2 > 1e6f) ? 1 : 0;
    if (blockIdx.x == 0) mode[0] = smode;
  }
  __syncthreads();
  int m = smode;
  int gid = blockIdx.x * 256 + threadIdx.x, stride = gridDim.x * 256;
  for (int i = gid; i < 8192; i += stride)
    W1b[i] = m ? f2bf(((const float*)W1r)[i]) : ((const u16*)W1r)[i];
  for (int i = gid; i < 1024; i += stride)
    W2f[i] = m ? ((const float*)W2r)[i] : bf2f(((const u16*)W2r)[i]);
  for (int i = gid; i < 64; i += stride)
    b1f[i] = m ? ((const float*)b1r)[i] : bf2f(((const u16*)b1r)[i]);
  for (int i = gid; i < 16; i += stride)
    b2f[i] = m ? ((const float*)b2r)[i] : bf2f(((const u16*)b2r)[i]);
}

// Partition edges into padded buckets (8192 edges/block, 512 threads).
__global__ __launch_bounds__(512) void kpart(const int* __restrict__ src,
                                             const int* __restrict__ dst,
                                             int* __restrict__ cursor,
                                             int* __restrict__ etmp,
                                             int E, int NB) {
  __shared__ int hist[1024], basep[1024];
  int tid = threadIdx.x;
  for (int i = tid; i < 1024; i += 512) hist[i] = 0;
  __syncthreads();
  int e0 = blockIdx.x * 8192 + tid * 16;
  int pk[16], off[16], cb[16];
  if (e0 + 15 < E) {
    int4 s4[4], d4[4];
    #pragma unroll
    for (int u = 0; u < 4; ++u) {
      s4[u] = ((const int4*)(src + e0))[u];
      d4[u] = ((const int4*)(dst + e0))[u];
    }
    const int* sp = (const int*)s4;
    const int* dp = (const int*)d4;
    #pragma unroll
    for (int k = 0; k < 16; ++k) {
      int s = sp[k], d = dp[k];
      cb[k] = d >> 7;
      pk[k] = (s << 7) | (d & 127);
      off[k] = atomicAdd(&hist[cb[k]], 1);
    }
  } else {
    #pragma unroll
    for (int k = 0; k < 16; ++k) {
      int e = e0 + k;
      cb[k] = -1;
      if (e < E) {
        int s = src[e], d = dst[e];
        cb[k] = d >> 7;
        pk[k] = (s << 7) | (d & 127);
        off[k] = atomicAdd(&hist[cb[k]], 1);
      }
    }
  }
  __syncthreads();
  for (int i = tid; i < NB; i += 512)
    if (hist[i]) basep[i] = atomicAdd(&cursor[i], hist[i]);
  __syncthreads();
  if (e0 + 15 < E) {
    #pragma unroll
    for (int k = 0; k < 16; ++k)
      etmp[cb[k] * CAP + basep[cb[k]] + off[k]] = pk[k];
  } else {
    #pragma unroll
    for (int k = 0; k < 16; ++k)
      if (cb[k] >= 0) etmp[cb[k] * CAP + basep[cb[k]] + off[k]] = pk[k];
  }
}

// Per bucket: LDS-staged counting sort by dst_low; in-place; rowse + dinv.
__global__ __launch_bounds__(512) void kfine(int* __restrict__ etmp,
                                             const int* __restrict__ cursor,
                                             int2* __restrict__ rowse,
                                             float* __restrict__ dinv, int N) {
  __shared__ int eL[CAP];
  __shared__ int hist[128], curs[128];
  int bk = blockIdx.x, tid = threadIdx.x;
  int cnt = cursor[bk];
  int base = bk * CAP;
  if (tid < 128) hist[tid] = 0;
  __syncthreads();
  for (int i = tid; i < cnt; i += 512) {
    int pk = etmp[base + i];
    eL[i] = pk;
    atomicAdd(&hist[pk & 127], 1);
  }
  __syncthreads();
  if (tid < 64) {
    int v0 = hist[tid], v1 = hist[tid + 64];
    int s0 = v0;
    #pragma unroll
    for (int off = 1; off < 64; off <<= 1) {
      int t = __shfl_up(s0, off, 64);
      if (tid >= off) s0 += t;
    }
    int tot0 = __shfl(s0, 63, 64);
    int s1 = v1;
    #pragma unroll
    for (int off = 1; off < 64; off <<= 1) {
      int t = __shfl_up(s1, off, 64);
      if (tid >= off) s1 += t;
    }
    s1 += tot0;
    int e0x = s0 - v0, e1x = s1 - v1;
    int node0 = (bk << 7) + tid, node1 = node0 + 64;
    if (node0 < N) {
      rowse[node0] = make_int2(base + e0x, base + e0x + v0);
      dinv[node0] = rsqrtf((float)(v0 + 1));
    }
    if (node1 < N) {
      rowse[node1] = make_int2(base + e1x, base + e1x + v1);
      dinv[node1] = rsqrtf((float)(v1 + 1));
    }
    curs[tid] = e0x;
    curs[tid + 64] = e1x;
  }
  __syncthreads();
  for (int i = tid; i < cnt; i += 512) {
    int pk = eL[i];
    int pos = atomicAdd(&curs[pk & 127], 1);
    etmp[base + pos] = pk >> 7;          // now holds sorted src index
  }
}

// h1s = (x @ W1) * dinv[row], bf16 out. One wave per 16-row tile.
__global__ __launch_bounds__(256) void kgemm1(const void* __restrict__ xraw,
                                              const u16* __restrict__ W1b,
                                              const int* __restrict__ mode,
                                              const float* __restrict__ dinv,
                                              u16* __restrict__ h1s, int n) {
  int mflag = mode[0];
  int wid = blockIdx.x * 4 + (threadIdx.x >> 6);
  int row0 = wid * 16;
  if (row0 >= n) return;
  int lane = threadIdx.x & 63;
  int m = lane & 15, q = lane >> 4;

  short8 bfrag[4][4];
  for (int jb = 0; jb < 4; ++jb)
    for (int kb = 0; kb < 4; ++kb) {
      short8 f;
      #pragma unroll
      for (int j = 0; j < 8; ++j)
        f[j] = (short)W1b[(kb * 32 + q * 8 + j) * 64 + jb * 16 + m];
      bfrag[jb][kb] = f;
    }

  f32x4 acc[4];
  #pragma unroll
  for (int jb = 0; jb < 4; ++jb) acc[jb] = (f32x4){0.f, 0.f, 0.f, 0.f};

  #pragma unroll
  for (int kb = 0; kb < 4; ++kb) {
    short8 a;
    if (mflag) {
      const float* xf = (const float*)xraw + (size_t)(row0 + m) * 128 + kb * 32 + q * 8;
      float4 u0 = ((const float4*)xf)[0];
      float4 u1 = ((const float4*)xf)[1];
      a[0] = (short)f2bf(u0.x); a[1] = (short)f2bf(u0.y);
      a[2] = (short)f2bf(u0.z); a[3] = (short)f2bf(u0.w);
      a[4] = (short)f2bf(u1.x); a[5] = (short)f2bf(u1.y);
      a[6] = (short)f2bf(u1.z); a[7] = (short)f2bf(u1.w);
    } else {
      a = *(const short8*)((const u16*)xraw + (size_t)(row0 + m) * 128 + kb * 32 + q * 8);
    }
    #pragma unroll
    for (int jb = 0; jb < 4; ++jb)
      acc[jb] = __builtin_amdgcn_mfma_f32_16x16x32_bf16(a, bfrag[jb][kb], acc[jb], 0, 0, 0);
  }

  #pragma unroll
  for (int r = 0; r < 4; ++r) {
    float dv = dinv[row0 + q * 4 + r];
    #pragma unroll
    for (int jb = 0; jb < 4; ++jb)
      h1s[(row0 + q * 4 + r) * 64 + jb * 16 + m] = f2bf(acc[jb][r] * dv);
  }
}

// Layer-1 aggregate + relu + fused GEMM2 -> h2sb (bf16).
// QUARTER-wave per node: ql=lane&15 owns features 4ql..4ql+3 (uint2 slice of
// the 128B row). One load instr = 4 edges (4 quarters). No cross-lane combine.
__global__ __launch_bounds__(256) void kagg1(
    const u16* __restrict__ h1s, const int* __restrict__ esort,
    const int2* __restrict__ rowse, const float* __restrict__ dinv,
    const float* __restrict__ b1f, const float* __restrict__ W2f,
    u16* __restrict__ h2sb, int n) {
  __shared__ float W2s[64 * 17];
  int tid = threadIdx.x;
  for (int i = tid; i < 1024; i += 256)
    W2s[(i >> 4) * 17 + (i & 15)] = W2f[i];
  __syncthreads();

  int lane = tid & 63, wv = tid >> 6;
  int ql = lane & 15, q = lane >> 4;
  int node = blockIdx.x * 16 + wv * 4 + q;
  if (node >= n) node = n - 1;
  int2 se = rowse[node];
  int beg = se.x, end = se.y;
  const uint2* h1v = (const uint2*)h1s;        // 16 uint2 per 64-feat row
  uint2 sg = h1v[node * 16 + ql];              // self row slice (early)
  float a0 = 0.f, a1 = 0.f, a2 = 0.f, a3 = 0.f;

  for (int base = beg; base < end; base += 16) {
    int idx = base + ql;
    int eidx = esort[(idx < end) ? idx : (end - 1)];   // 16-wide coalesced
    int cnt = min(16, end - base);
    int k = 0;
    for (; k + 8 <= cnt; k += 8) {          // 8 gathers in flight per quarter
      uint2 g[8];
      #pragma unroll
      for (int p = 0; p < 8; ++p) {
        int s = __shfl(eidx, k + p, 16);
        g[p] = h1v[s * 16 + ql];
      }
      #pragma unroll
      for (int p = 0; p < 8; ++p) {
        a0 += bf2f((u16)(g[p].x & 0xffff));
        a1 += bf2f((u16)(g[p].x >> 16));
        a2 += bf2f((u16)(g[p].y & 0xffff));
        a3 += bf2f((u16)(g[p].y >> 16));
      }
    }
    for (; k < cnt; ++k) {
      int s = __shfl(eidx, k, 16);
      uint2 g = h1v[s * 16 + ql];
      a0 += bf2f((u16)(g.x & 0xffff));
      a1 += bf2f((u16)(g.x >> 16));
      a2 += bf2f((u16)(g.y & 0xffff));
      a3 += bf2f((u16)(g.y >> 16));
    }
  }

  float dv = dinv[node];
  float4 b1v = ((const float4*)b1f)[ql];
  float vr0 = fmaxf(dv * (a0 + bf2f((u16)(sg.x & 0xffff))) + b1v.x, 0.f);
  float vr1 = fmaxf(dv * (a1 + bf2f((u16)(sg.x >> 16))) + b1v.y, 0.f);
  float vr2 = fmaxf(dv * (a2 + bf2f((u16)(sg.y & 0xffff))) + b1v.z, 0.f);
  float vr3 = fmaxf(dv * (a3 + bf2f((u16)(sg.y >> 16))) + b1v.w, 0.f);

  // GEMM2 epilogue: lane computes class c=ql of its node.
  // feature j lives at quarter-lane j>>2, slot j&3 -> width-16 shfl broadcast.
  float p = 0.f;
  #pragma unroll
  for (int j = 0; j < 64; ++j) {
    float vj;
    switch (j & 3) {
      case 0: vj = __shfl(vr0, j >> 2, 16); break;
      case 1: vj = __shfl(vr1, j >> 2, 16); break;
      case 2: vj = __shfl(vr2, j >> 2, 16); break;
      default: vj = __shfl(vr3, j >> 2, 16); break;
    }
    p = fmaf(vj, W2s[j * 17 + ql], p);
  }
  h2sb[node * 16 + ql] = f2bf(p * dv);
}

// Layer-2 aggregate + bias + relu + log_softmax.
// OCT per node: ol=lane&7 owns classes 2ol..2ol+1 (dword slice of 32B row).
// One load instr = 8 edges. Width-8 shfl softmax.
__global__ __launch_bounds__(256) void kagg2(
    const u16* __restrict__ h2sb, const int* __restrict__ esort,
    const int2* __restrict__ rowse, const float* __restrict__ dinv,
    const float* __restrict__ b2f, const int* __restrict__ mode,
    void* __restrict__ out, int n) {
  int mflag = mode[0];
  int tid = threadIdx.x;
  int lane = tid & 63, wv = tid >> 6;
  int ol = lane & 7, oc = lane >> 3;
  int node = blockIdx.x * 32 + wv * 8 + oc;
  if (node >= n) node = n - 1;
  int2 se = rowse[node];
  int beg = se.x, end = se.y;
  const unsigned int* h2v = (const unsigned int*)h2sb;   // 8 dwords/row
  unsigned int sg = h2v[node * 8 + ol];
  float ax = 0.f, ay = 0.f;

  for (int base = beg; base < end; base += 8) {
    int idx = base + ol;
    int eidx = esort[(idx < end) ? idx : (end - 1)];     // 8-wide
    int cnt = min(8, end - base);
    int k = 0;
    for (; k + 8 <= cnt; k += 8) {
      unsigned int g[8];
      #pragma unroll
      for (int p = 0; p < 8; ++p) {
        int s = __shfl(eidx, k + p, 8);
        g[p] = h2v[s * 8 + ol];
      }
      #pragma unroll
      for (int p = 0; p < 8; ++p) {
        ax += bf2f((u16)(g[p] & 0xffff));
        ay += bf2f((u16)(g[p] >> 16));
      }
    }
    for (; k < cnt; ++k) {
      int s = __shfl(eidx, k, 8);
      unsigned int g = h2v[s * 8 + ol];
      ax += bf2f((u16)(g & 0xffff));
      ay += bf2f((u16)(g >> 16));
    }
  }

  float dv = dinv[node];
  float2 b2v = ((const float2*)b2f)[ol];
  float vx = fmaxf(dv * (ax + bf2f((u16)(sg & 0xffff))) + b2v.x, 0.f);
  float vy = fmaxf(dv * (ay + bf2f((u16)(sg >> 16))) + b2v.y, 0.f);

  float m = fmaxf(vx, vy);
  #pragma unroll
  for (int off = 1; off <= 4; off <<= 1) m = fmaxf(m, __shfl_xor(m, off, 8));
  float ex = __expf(vx - m) + __expf(vy - m);
  #pragma unroll
  for (int off = 1; off <= 4; off <<= 1) ex += __shfl_xor(ex, off, 8);
  float lg = __logf(ex);
  float rx = vx - m - lg, ry = vy - m - lg;
  if (mflag) ((float2*)out)[(size_t)node * 8 + ol] = make_float2(rx, ry);
  else ((unsigned int*)out)[(size_t)node * 8 + ol] =
         (unsigned int)f2bf(rx) | ((unsigned int)f2bf(ry) << 16);
}

extern "C" void kernel_launch(void* const* d_in, const int* in_sizes, int n_in,
                              void* d_out, int out_size, void* d_ws, size_t ws_size,
                              hipStream_t stream) {
  const void* x  = d_in[0];
  const int* ei  = (const int*)d_in[1];
  const void* W1 = d_in[2];
  const void* b1 = d_in[3];
  const void* W2 = d_in[4];
  const void* b2 = d_in[5];

  const int N = in_sizes[0] / 128;
  const int E = in_sizes[1] / 2;
  const int* src = ei;
  const int* dst = ei + E;
  const int NB = (N + 127) >> 7;          // 128-node buckets

  char* ws = (char*)d_ws;
  size_t off = 0;
  auto alloc = [&](size_t bytes) -> char* {
    char* p = ws + off;
    off = (off + bytes + 255) & ~(size_t)255;
    return p;
  };
  u16*   h1s    = (u16*)  alloc((size_t)N * 64 * 2);
  u16*   h2sb   = (u16*)  alloc((size_t)N * 16 * 2);
  int*   etmp   = (int*)  alloc((size_t)NB * CAP * 4);   // packed, then sorted src
  float* dinv   = (float*)alloc((size_t)N * 4);
  int2*  rowse  = (int2*) alloc((size_t)N * 8);
  int*   cursor = (int*)  alloc((size_t)NB * 4);
  u16*   W1b    = (u16*)  alloc(8192 * 2);
  float* W2f    = (float*)alloc(1024 * 4);
  float* b1f    = (float*)alloc(64 * 4);
  float* b2f    = (float*)alloc(16 * 4);
  int*   mode   = (int*)  alloc(4);

  hipMemsetAsync(cursor, 0, (size_t)NB * 4, stream);

  kconvw<<<32, 256, 0, stream>>>(W1, b1, W2, b2, W1b, b1f, W2f, b2f, mode);

  kpart<<<(E + 8191) / 8192, 512, 0, stream>>>(src, dst, cursor, etmp, E, NB);
  kfine<<<NB, 512, 0, stream>>>(etmp, cursor, rowse, dinv, N);

  int tiles = (N + 15) / 16;
  kgemm1<<<(tiles + 3) / 4, 256, 0, stream>>>(x, W1b, mode, dinv, h1s, N);
  kagg1<<<(N + 15) / 16, 256, 0, stream>>>(h1s, etmp, rowse, dinv, b1f, W2f, h2sb, N);
  kagg2<<<(N + 31) / 32, 256, 0, stream>>>(h2sb, etmp, rowse, dinv, b2f, mode, d_out, N);
}